// Round 1
// baseline (181.136 us; speedup 1.0000x reference)
//
#include <hip/hip_runtime.h>
#include <stdint.h>

#define BB 4
#define NN 4096
#define CC 256
#define DD 32

typedef __bf16 bf16;
typedef bf16 bf16x4 __attribute__((ext_vector_type(4)));
typedef bf16 bf16x8 __attribute__((ext_vector_type(8)));
typedef float f32x4 __attribute__((ext_vector_type(4)));
typedef unsigned int u32x4 __attribute__((ext_vector_type(4)));

// ---------------- prep: cast x -> bf16, build WT[320][256] = [Wq|Wk|Wv]^T ----
__global__ void prep_kernel(const float* __restrict__ x,
                            const float* __restrict__ Wq,
                            const float* __restrict__ Wk,
                            const float* __restrict__ Wv,
                            bf16* __restrict__ xb,
                            bf16* __restrict__ WT)
{
    int gt = blockIdx.x * blockDim.x + threadIdx.x;
    int stride = gridDim.x * blockDim.x;
    const int total4 = BB * NN * CC / 4;
    for (int i = gt; i < total4; i += stride) {
        f32x4 v = ((const f32x4*)x)[i];
        bf16x4 o;
        o[0] = (bf16)v[0]; o[1] = (bf16)v[1]; o[2] = (bf16)v[2]; o[3] = (bf16)v[3];
        ((bf16x4*)xb)[i] = o;
    }
    const int wtot = 320 * 256;
    for (int i = gt; i < wtot; i += stride) {
        int d = i >> 8, c = i & 255;
        float val;
        if (d < DD)          val = Wq[c * DD + d];
        else if (d < 2 * DD) val = Wk[c * DD + (d - DD)];
        else                 val = Wv[c * CC + (d - 2 * DD)];
        WT[i] = (bf16)val;
    }
}

// ---------------- proj: [q|k|v] = x @ [Wq|Wk|Wv] via MFMA -------------------
// Outputs: qb,kb as [B][N][32] bf16; v transposed+swizzled:
//   vt elem offset = ((b*64 + tile)*256 + c)*64 + (n_in_tile ^ ((c&7)<<3))
__global__ __launch_bounds__(256) void proj_kernel(
    const bf16* __restrict__ xb, const bf16* __restrict__ WT,
    bf16* __restrict__ qb, bf16* __restrict__ kb, bf16* __restrict__ vt)
{
    int b = blockIdx.x >> 6, nt = blockIdx.x & 63;
    int n0 = nt << 6;
    int tid = threadIdx.x;
    int wid = tid >> 6, lane = tid & 63;
    int lm = lane & 15, g = lane >> 4;

    f32x4 acc[20];
    f32x4 zero4 = {0.f, 0.f, 0.f, 0.f};
#pragma unroll
    for (int i = 0; i < 20; ++i) acc[i] = zero4;

    const bf16* xrow = xb + ((size_t)(b * NN) + n0 + wid * 16 + lm) * CC;
    for (int kc = 0; kc < 8; ++kc) {
        bf16x8 a = *(const bf16x8*)(xrow + kc * 32 + g * 8);
#pragma unroll
        for (int ct = 0; ct < 20; ++ct) {
            bf16x8 w = *(const bf16x8*)(WT + (ct * 16 + lm) * 256 + kc * 32 + g * 8);
            acc[ct] = __builtin_amdgcn_mfma_f32_16x16x32_bf16(a, w, acc[ct], 0, 0, 0);
        }
    }

#pragma unroll
    for (int ct = 0; ct < 20; ++ct) {
        int col = ct * 16 + lm;
        if (ct < 4) {
#pragma unroll
            for (int r = 0; r < 4; ++r) {
                int n = n0 + wid * 16 + g * 4 + r;
                bf16 hv = (bf16)acc[ct][r];
                if (ct < 2) qb[((size_t)(b * NN) + n) * DD + col] = hv;
                else        kb[((size_t)(b * NN) + n) * DD + (col - DD)] = hv;
            }
        } else {
            int c = col - 64;
            int nbase = (wid * 16 + g * 4) ^ ((c & 7) << 3); // XOR only touches bits>=3
            bf16x4 pk;
            pk[0] = (bf16)acc[ct][0]; pk[1] = (bf16)acc[ct][1];
            pk[2] = (bf16)acc[ct][2]; pk[3] = (bf16)acc[ct][3];
            size_t off = (((size_t)(b * 64 + nt)) * 256 + c) * 64 + nbase;
            *(bf16x4*)(vt + off) = pk;
        }
    }
}

// ---------------- attn: flash attention, online softmax, MFMA ---------------
__global__ __launch_bounds__(256) void attn_kernel(
    const bf16* __restrict__ qb, const bf16* __restrict__ kb,
    const bf16* __restrict__ vt, const float* __restrict__ x,
    const float* __restrict__ gamma, float* __restrict__ out)
{
    __shared__ __align__(16) unsigned char lds[40960]; // 32KB V tile + 4*2KB P
    int b = blockIdx.x >> 6, qt = blockIdx.x & 63;
    int n0 = qt << 6;
    int tid = threadIdx.x;
    int wid = tid >> 6, lane = tid & 63;
    int lm = lane & 15, g = lane >> 4;

    // Q A-fragment: row = lane%16, k = 8*(lane>>4)+j  (16B contiguous)
    bf16x8 qf = *(const bf16x8*)(qb + ((size_t)(b * NN) + n0 + wid * 16 + lm) * DD + g * 8);

    f32x4 acc[16];
    f32x4 zero4 = {0.f, 0.f, 0.f, 0.f};
#pragma unroll
    for (int i = 0; i < 16; ++i) acc[i] = zero4;
    float mrow[4] = {-3e38f, -3e38f, -3e38f, -3e38f};
    float lrow[4] = {0.f, 0.f, 0.f, 0.f};

    const u32x4* vsrc = (const u32x4*)(vt + (size_t)b * (64 * 256 * 64));
    u32x4* vlds = (u32x4*)lds;
    unsigned char* plds = lds + 32768 + wid * 2048;

    for (int kt = 0; kt < 64; ++kt) {
        // K B-fragments straight from global (L2-resident), col=lane%16=key
        const bf16* kbase = kb + ((size_t)(b * NN) + kt * 64) * DD;
        bf16x8 kf0 = *(const bf16x8*)(kbase + (lm +  0) * DD + g * 8);
        bf16x8 kf1 = *(const bf16x8*)(kbase + (lm + 16) * DD + g * 8);
        bf16x8 kf2 = *(const bf16x8*)(kbase + (lm + 32) * DD + g * 8);
        bf16x8 kf3 = *(const bf16x8*)(kbase + (lm + 48) * DD + g * 8);

        __syncthreads(); // previous iteration's LDS reads complete
        const u32x4* tsrc = vsrc + (size_t)kt * 2048;
#pragma unroll
        for (int i = 0; i < 8; ++i) vlds[i * 256 + tid] = tsrc[i * 256 + tid];
        __syncthreads(); // V tile ready

        f32x4 sv[4];
        sv[0] = __builtin_amdgcn_mfma_f32_16x16x32_bf16(qf, kf0, zero4, 0, 0, 0);
        sv[1] = __builtin_amdgcn_mfma_f32_16x16x32_bf16(qf, kf1, zero4, 0, 0, 0);
        sv[2] = __builtin_amdgcn_mfma_f32_16x16x32_bf16(qf, kf2, zero4, 0, 0, 0);
        sv[3] = __builtin_amdgcn_mfma_f32_16x16x32_bf16(qf, kf3, zero4, 0, 0, 0);

        // online softmax; S[row=4g+r][col=16t+lm]; row-reduce = shfl over lm
        float alpha[4], mnew[4];
#pragma unroll
        for (int r = 0; r < 4; ++r) {
            float mx = fmaxf(fmaxf(sv[0][r], sv[1][r]), fmaxf(sv[2][r], sv[3][r]));
            mx = fmaxf(mx, __shfl_xor(mx, 1));
            mx = fmaxf(mx, __shfl_xor(mx, 2));
            mx = fmaxf(mx, __shfl_xor(mx, 4));
            mx = fmaxf(mx, __shfl_xor(mx, 8));
            float mn = fmaxf(mrow[r], mx);
            alpha[r] = __expf(mrow[r] - mn);
            mnew[r] = mn;
            mrow[r] = mn;
        }
        float ps[4][4];
#pragma unroll
        for (int r = 0; r < 4; ++r) {
            float sum = 0.f;
#pragma unroll
            for (int t = 0; t < 4; ++t) {
                float p = __expf(sv[t][r] - mnew[r]);
                ps[t][r] = p;
                sum += p;
            }
            sum += __shfl_xor(sum, 1);
            sum += __shfl_xor(sum, 2);
            sum += __shfl_xor(sum, 4);
            sum += __shfl_xor(sum, 8);
            lrow[r] = lrow[r] * alpha[r] + sum;
        }
#pragma unroll
        for (int ct = 0; ct < 16; ++ct) {
#pragma unroll
            for (int r = 0; r < 4; ++r) acc[ct][r] *= alpha[r];
        }
        // write P tile [16q x 64k] bf16 to this wave's LDS region (swizzled)
#pragma unroll
        for (int t = 0; t < 4; ++t) {
#pragma unroll
            for (int r = 0; r < 4; ++r) {
                int row = g * 4 + r;
                int byteo = row * 128 + ((32 * t + 2 * lm) ^ ((row & 7) << 4));
                *(bf16*)(plds + byteo) = (bf16)ps[t][r];
            }
        }
        asm volatile("s_waitcnt lgkmcnt(0)" ::: "memory"); // wave-local P visibility
        // P A-frags: row=lm, k chunks 0-31 / 32-63
        bf16x8 pa0 = *(const bf16x8*)(plds + lm * 128 + ((0 + 16 * g) ^ ((lm & 7) << 4)));
        bf16x8 pa1 = *(const bf16x8*)(plds + lm * 128 + ((64 + 16 * g) ^ ((lm & 7) << 4)));
#pragma unroll
        for (int ct = 0; ct < 16; ++ct) {
            int c = ct * 16 + lm;
            const unsigned char* vbp = lds + c * 128;
            bf16x8 v0 = *(const bf16x8*)(vbp + ((0 + 16 * g) ^ ((c & 7) << 4)));
            acc[ct] = __builtin_amdgcn_mfma_f32_16x16x32_bf16(pa0, v0, acc[ct], 0, 0, 0);
            bf16x8 v1 = *(const bf16x8*)(vbp + ((64 + 16 * g) ^ ((c & 7) << 4)));
            acc[ct] = __builtin_amdgcn_mfma_f32_16x16x32_bf16(pa1, v1, acc[ct], 0, 0, 0);
        }
    }

    float inv[4];
#pragma unroll
    for (int r = 0; r < 4; ++r) inv[r] = 1.0f / lrow[r];
    float gam = gamma[0];
#pragma unroll
    for (int ct = 0; ct < 16; ++ct) {
        int col = ct * 16 + lm;
#pragma unroll
        for (int r = 0; r < 4; ++r) {
            int n = n0 + wid * 16 + g * 4 + r;
            size_t idx = ((size_t)(b * NN) + n) * CC + col;
            out[idx] = x[idx] + gam * acc[ct][r] * inv[r];
        }
    }
}

extern "C" void kernel_launch(void* const* d_in, const int* in_sizes, int n_in,
                              void* d_out, int out_size, void* d_ws, size_t ws_size,
                              hipStream_t stream)
{
    const float* x     = (const float*)d_in[0];
    const float* Wq    = (const float*)d_in[1];
    const float* Wk    = (const float*)d_in[2];
    const float* Wv    = (const float*)d_in[3];
    const float* gamma = (const float*)d_in[4];
    float* out = (float*)d_out;

    char* ws = (char*)d_ws;
    bf16* xb = (bf16*)(ws);                  // 8,388,608 B
    bf16* WT = (bf16*)(ws + 8388608);        //   163,840 B
    bf16* qb = (bf16*)(ws + 8552448);        // 1,048,576 B
    bf16* kb = (bf16*)(ws + 9601024);        // 1,048,576 B
    bf16* vt = (bf16*)(ws + 10649600);       // 8,388,608 B  (end ~19.04 MB)

    hipLaunchKernelGGL(prep_kernel, dim3(1024), dim3(256), 0, stream,
                       x, Wq, Wk, Wv, xb, WT);
    hipLaunchKernelGGL(proj_kernel, dim3(256), dim3(256), 0, stream,
                       xb, WT, qb, kb, vt);
    hipLaunchKernelGGL(attn_kernel, dim3(256), dim3(256), 0, stream,
                       qb, kb, vt, x, gamma, out);
}

// Round 2
// 152.230 us; speedup vs baseline: 1.1899x; 1.1899x over previous
//
#include <hip/hip_runtime.h>
#include <stdint.h>

#define BB 4
#define NN 4096
#define CC 256
#define DD 32

typedef __bf16 bf16;
typedef bf16 bf16x4 __attribute__((ext_vector_type(4)));
typedef bf16 bf16x8 __attribute__((ext_vector_type(8)));
typedef float f32x4 __attribute__((ext_vector_type(4)));
typedef unsigned int u32x4 __attribute__((ext_vector_type(4)));

// ---------------- prep: cast x -> bf16, build WT[320][256] = [Wq|Wk|Wv]^T ----
__global__ void prep_kernel(const float* __restrict__ x,
                            const float* __restrict__ Wq,
                            const float* __restrict__ Wk,
                            const float* __restrict__ Wv,
                            bf16* __restrict__ xb,
                            bf16* __restrict__ WT)
{
    int gt = blockIdx.x * blockDim.x + threadIdx.x;
    int stride = gridDim.x * blockDim.x;
    const int total4 = BB * NN * CC / 4;
    for (int i = gt; i < total4; i += stride) {
        f32x4 v = ((const f32x4*)x)[i];
        bf16x4 o;
        o[0] = (bf16)v[0]; o[1] = (bf16)v[1]; o[2] = (bf16)v[2]; o[3] = (bf16)v[3];
        ((bf16x4*)xb)[i] = o;
    }
    const int wtot = 320 * 256;
    for (int i = gt; i < wtot; i += stride) {
        int d = i >> 8, c = i & 255;
        float val;
        if (d < DD)          val = Wq[c * DD + d];
        else if (d < 2 * DD) val = Wk[c * DD + (d - DD)];
        else                 val = Wv[c * CC + (d - 2 * DD)];
        WT[i] = (bf16)val;
    }
}

// ---------------- proj: [q|k|v] = x @ [Wq|Wk|Wv] via MFMA -------------------
// Outputs: qb,kb as [B][N][32] bf16; v transposed+swizzled:
//   vt elem offset = ((b*64 + tile)*256 + c)*64 + (n_in_tile ^ ((c&7)<<3))
__global__ __launch_bounds__(256) void proj_kernel(
    const bf16* __restrict__ xb, const bf16* __restrict__ WT,
    bf16* __restrict__ qb, bf16* __restrict__ kb, bf16* __restrict__ vt)
{
    int b = blockIdx.x >> 6, nt = blockIdx.x & 63;
    int n0 = nt << 6;
    int tid = threadIdx.x;
    int wid = tid >> 6, lane = tid & 63;
    int lm = lane & 15, g = lane >> 4;

    f32x4 acc[20];
    f32x4 zero4 = {0.f, 0.f, 0.f, 0.f};
#pragma unroll
    for (int i = 0; i < 20; ++i) acc[i] = zero4;

    const bf16* xrow = xb + ((size_t)(b * NN) + n0 + wid * 16 + lm) * CC;
    for (int kc = 0; kc < 8; ++kc) {
        bf16x8 a = *(const bf16x8*)(xrow + kc * 32 + g * 8);
#pragma unroll
        for (int ct = 0; ct < 20; ++ct) {
            bf16x8 w = *(const bf16x8*)(WT + (ct * 16 + lm) * 256 + kc * 32 + g * 8);
            acc[ct] = __builtin_amdgcn_mfma_f32_16x16x32_bf16(a, w, acc[ct], 0, 0, 0);
        }
    }

#pragma unroll
    for (int ct = 0; ct < 20; ++ct) {
        int col = ct * 16 + lm;
        if (ct < 4) {
#pragma unroll
            for (int r = 0; r < 4; ++r) {
                int n = n0 + wid * 16 + g * 4 + r;
                bf16 hv = (bf16)acc[ct][r];
                if (ct < 2) qb[((size_t)(b * NN) + n) * DD + col] = hv;
                else        kb[((size_t)(b * NN) + n) * DD + (col - DD)] = hv;
            }
        } else {
            int c = col - 64;
            int nbase = (wid * 16 + g * 4) ^ ((c & 7) << 3); // XOR only touches bits>=3
            bf16x4 pk;
            pk[0] = (bf16)acc[ct][0]; pk[1] = (bf16)acc[ct][1];
            pk[2] = (bf16)acc[ct][2]; pk[3] = (bf16)acc[ct][3];
            size_t off = (((size_t)(b * 64 + nt)) * 256 + c) * 64 + nbase;
            *(bf16x4*)(vt + off) = pk;
        }
    }
}

// ---------------- attn: flash attention, online softmax, split-K ------------
// KS = key-split factor; block handles 64 q rows x (4096/KS) keys.
// KS>1: writes partial acc (unnormalized, fp32) + per-row (m,l) to ws.
// KS==1: writes final out directly (round-1 behavior).
__global__ __launch_bounds__(256) void attn_kernel(
    const bf16* __restrict__ qb, const bf16* __restrict__ kb,
    const bf16* __restrict__ vt, const float* __restrict__ x,
    const float* __restrict__ gamma, float* __restrict__ pacc,
    float* __restrict__ pml, float* __restrict__ out, int KS)
{
    __shared__ __align__(16) unsigned char lds[40960]; // 32KB V tile + 4*2KB P
    int bid = blockIdx.x;
    int b, qt, ks;
    if (KS == 4) {
        // XCD-aware decode: batch b -> XCDs {2b, 2b+1} so vt/kb are L2-resident
        int xcd = bid & 7, slot = bid >> 3;     // 1024 blocks: slot in [0,128)
        b = xcd >> 1;
        int idx = (xcd & 1) * 128 + slot;       // [0,256) within batch
        qt = idx >> 2; ks = idx & 3;
    } else {
        ks = bid % KS; int t = bid / KS; b = t >> 6; qt = t & 63;
    }
    int bq = b * 64 + qt;
    int n0 = qt << 6;
    int tid = threadIdx.x;
    int wid = tid >> 6, lane = tid & 63;
    int lm = lane & 15, g = lane >> 4;

    // Q A-fragment: row = lane%16, k = 8*(lane>>4)+j  (16B contiguous)
    bf16x8 qf = *(const bf16x8*)(qb + ((size_t)(b * NN) + n0 + wid * 16 + lm) * DD + g * 8);

    f32x4 acc[16];
    f32x4 zero4 = {0.f, 0.f, 0.f, 0.f};
#pragma unroll
    for (int i = 0; i < 16; ++i) acc[i] = zero4;
    float mrow[4] = {-3e38f, -3e38f, -3e38f, -3e38f};
    float lrow[4] = {0.f, 0.f, 0.f, 0.f};

    const u32x4* vsrc = (const u32x4*)(vt + (size_t)b * (64 * 256 * 64));
    u32x4* vlds = (u32x4*)lds;
    unsigned char* plds = lds + 32768 + wid * 2048;

    int KT = 64 / KS;
    int kt0 = ks * KT;
    for (int kt = kt0; kt < kt0 + KT; ++kt) {
        // K B-fragments straight from global (L2-resident), col=lane%16=key
        const bf16* kbase = kb + ((size_t)(b * NN) + kt * 64) * DD;
        bf16x8 kf0 = *(const bf16x8*)(kbase + (lm +  0) * DD + g * 8);
        bf16x8 kf1 = *(const bf16x8*)(kbase + (lm + 16) * DD + g * 8);
        bf16x8 kf2 = *(const bf16x8*)(kbase + (lm + 32) * DD + g * 8);
        bf16x8 kf3 = *(const bf16x8*)(kbase + (lm + 48) * DD + g * 8);

        __syncthreads(); // previous iteration's LDS reads complete
        const u32x4* tsrc = vsrc + (size_t)kt * 2048;
#pragma unroll
        for (int i = 0; i < 8; ++i) vlds[i * 256 + tid] = tsrc[i * 256 + tid];
        __syncthreads(); // V tile ready

        f32x4 sv[4];
        sv[0] = __builtin_amdgcn_mfma_f32_16x16x32_bf16(qf, kf0, zero4, 0, 0, 0);
        sv[1] = __builtin_amdgcn_mfma_f32_16x16x32_bf16(qf, kf1, zero4, 0, 0, 0);
        sv[2] = __builtin_amdgcn_mfma_f32_16x16x32_bf16(qf, kf2, zero4, 0, 0, 0);
        sv[3] = __builtin_amdgcn_mfma_f32_16x16x32_bf16(qf, kf3, zero4, 0, 0, 0);

        // online softmax; S[row=4g+r][col=16t+lm]; row-reduce = shfl over lm
        float alpha[4], mnew[4];
#pragma unroll
        for (int r = 0; r < 4; ++r) {
            float mx = fmaxf(fmaxf(sv[0][r], sv[1][r]), fmaxf(sv[2][r], sv[3][r]));
            mx = fmaxf(mx, __shfl_xor(mx, 1));
            mx = fmaxf(mx, __shfl_xor(mx, 2));
            mx = fmaxf(mx, __shfl_xor(mx, 4));
            mx = fmaxf(mx, __shfl_xor(mx, 8));
            float mn = fmaxf(mrow[r], mx);
            alpha[r] = __expf(mrow[r] - mn);
            mnew[r] = mn;
            mrow[r] = mn;
        }
        float ps[4][4];
#pragma unroll
        for (int r = 0; r < 4; ++r) {
            float sum = 0.f;
#pragma unroll
            for (int t = 0; t < 4; ++t) {
                float p = __expf(sv[t][r] - mnew[r]);
                ps[t][r] = p;
                sum += p;
            }
            sum += __shfl_xor(sum, 1);
            sum += __shfl_xor(sum, 2);
            sum += __shfl_xor(sum, 4);
            sum += __shfl_xor(sum, 8);
            lrow[r] = lrow[r] * alpha[r] + sum;
        }
#pragma unroll
        for (int ct = 0; ct < 16; ++ct) {
#pragma unroll
            for (int r = 0; r < 4; ++r) acc[ct][r] *= alpha[r];
        }
        // write P tile [16q x 64k] bf16 to this wave's LDS region (swizzled)
#pragma unroll
        for (int t = 0; t < 4; ++t) {
#pragma unroll
            for (int r = 0; r < 4; ++r) {
                int row = g * 4 + r;
                int byteo = row * 128 + ((32 * t + 2 * lm) ^ ((row & 7) << 4));
                *(bf16*)(plds + byteo) = (bf16)ps[t][r];
            }
        }
        asm volatile("s_waitcnt lgkmcnt(0)" ::: "memory"); // wave-local P visibility
        // P A-frags: row=lm, k chunks 0-31 / 32-63
        bf16x8 pa0 = *(const bf16x8*)(plds + lm * 128 + ((0 + 16 * g) ^ ((lm & 7) << 4)));
        bf16x8 pa1 = *(const bf16x8*)(plds + lm * 128 + ((64 + 16 * g) ^ ((lm & 7) << 4)));
#pragma unroll
        for (int ct = 0; ct < 16; ++ct) {
            int c = ct * 16 + lm;
            const unsigned char* vbp = lds + c * 128;
            bf16x8 v0 = *(const bf16x8*)(vbp + ((0 + 16 * g) ^ ((c & 7) << 4)));
            acc[ct] = __builtin_amdgcn_mfma_f32_16x16x32_bf16(pa0, v0, acc[ct], 0, 0, 0);
            bf16x8 v1 = *(const bf16x8*)(vbp + ((64 + 16 * g) ^ ((c & 7) << 4)));
            acc[ct] = __builtin_amdgcn_mfma_f32_16x16x32_bf16(pa1, v1, acc[ct], 0, 0, 0);
        }
    }

    if (KS == 1) {
        float inv[4];
#pragma unroll
        for (int r = 0; r < 4; ++r) inv[r] = 1.0f / lrow[r];
        float gam = gamma[0];
#pragma unroll
        for (int ct = 0; ct < 16; ++ct) {
            int col = ct * 16 + lm;
#pragma unroll
            for (int r = 0; r < 4; ++r) {
                int n = n0 + wid * 16 + g * 4 + r;
                size_t idx = ((size_t)(b * NN) + n) * CC + col;
                out[idx] = x[idx] + gam * acc[ct][r] * inv[r];
            }
        }
    } else {
        float* pa = pacc + ((size_t)(bq * KS + ks)) * (64 * 256);
#pragma unroll
        for (int ct = 0; ct < 16; ++ct) {
            int col = ct * 16 + lm;
#pragma unroll
            for (int r = 0; r < 4; ++r) {
                int rowin = wid * 16 + g * 4 + r;
                pa[rowin * 256 + col] = acc[ct][r];
            }
        }
        if (lm == 0) {
#pragma unroll
            for (int r = 0; r < 4; ++r) {
                int rowin = wid * 16 + g * 4 + r;
                size_t mo = ((size_t)(bq * KS + ks) * 64 + rowin) * 2;
                pml[mo + 0] = mrow[r];
                pml[mo + 1] = lrow[r];
            }
        }
    }
}

// ---------------- combine: merge KS partials + residual epilogue ------------
__global__ __launch_bounds__(256) void combine_kernel(
    const float* __restrict__ pacc, const float* __restrict__ pml,
    const float* __restrict__ x, const float* __restrict__ gamma,
    float* __restrict__ out, int KS)
{
    int tid = threadIdx.x;
    int row = blockIdx.x * 4 + (tid >> 6);   // global row in [0, B*N)
    int lane = tid & 63;
    int bq = row >> 6;
    int r64 = row & 63;

    float m[4], l[4];
    float M = -3e38f;
    for (int ks = 0; ks < KS; ++ks) {
        size_t mo = ((size_t)(bq * KS + ks) * 64 + r64) * 2;
        m[ks] = pml[mo + 0];
        l[ks] = pml[mo + 1];
        M = fmaxf(M, m[ks]);
    }
    float L = 0.f;
    float w[4];
    for (int ks = 0; ks < KS; ++ks) {
        w[ks] = __expf(m[ks] - M);
        L += w[ks] * l[ks];
    }
    float s = gamma[0] / L;

    f32x4 a = {0.f, 0.f, 0.f, 0.f};
    for (int ks = 0; ks < KS; ++ks) {
        const f32x4* pa = (const f32x4*)(pacc + ((size_t)(bq * KS + ks) * 64 + r64) * 256);
        f32x4 v = pa[lane];
        a[0] += w[ks] * v[0]; a[1] += w[ks] * v[1];
        a[2] += w[ks] * v[2]; a[3] += w[ks] * v[3];
    }
    const f32x4* xv = (const f32x4*)(x + (size_t)row * 256);
    f32x4 xi = xv[lane];
    f32x4 o;
    o[0] = xi[0] + s * a[0]; o[1] = xi[1] + s * a[1];
    o[2] = xi[2] + s * a[2]; o[3] = xi[3] + s * a[3];
    ((f32x4*)(out + (size_t)row * 256))[lane] = o;
}

extern "C" void kernel_launch(void* const* d_in, const int* in_sizes, int n_in,
                              void* d_out, int out_size, void* d_ws, size_t ws_size,
                              hipStream_t stream)
{
    const float* x     = (const float*)d_in[0];
    const float* Wq    = (const float*)d_in[1];
    const float* Wk    = (const float*)d_in[2];
    const float* Wv    = (const float*)d_in[3];
    const float* gamma = (const float*)d_in[4];
    float* out = (float*)d_out;

    char* ws = (char*)d_ws;
    bf16* xb = (bf16*)(ws);                  // 8,388,608 B
    bf16* WT = (bf16*)(ws + 8388608);        //   163,840 B
    bf16* qb = (bf16*)(ws + 8552448);        // 1,048,576 B
    bf16* kb = (bf16*)(ws + 9601024);        // 1,048,576 B
    bf16* vt = (bf16*)(ws + 10649600);       // 8,388,608 B  (end 19,038,208)

    const size_t base = 19038208;
    // per-KS partial bytes: acc = KS*256*64*256*4, ml = KS*256*64*2*4
    size_t need4 = base + (size_t)4 * (16777216 + 131072);
    size_t need2 = base + (size_t)2 * (16777216 + 131072);
    int KS = (ws_size >= need4) ? 4 : ((ws_size >= need2) ? 2 : 1);

    float* pacc = (float*)(ws + base);
    float* pml  = (float*)(ws + base + (size_t)KS * 16777216);

    hipLaunchKernelGGL(prep_kernel, dim3(1024), dim3(256), 0, stream,
                       x, Wq, Wk, Wv, xb, WT);
    hipLaunchKernelGGL(proj_kernel, dim3(256), dim3(256), 0, stream,
                       xb, WT, qb, kb, vt);
    hipLaunchKernelGGL(attn_kernel, dim3(256 * KS), dim3(256), 0, stream,
                       qb, kb, vt, x, gamma, pacc, pml, out, KS);
    if (KS > 1) {
        hipLaunchKernelGGL(combine_kernel, dim3(BB * NN / 4), dim3(256), 0, stream,
                           pacc, pml, x, gamma, out, KS);
    }
}